// Round 3
// baseline (75.344 us; speedup 1.0000x reference)
//
#include <hip/hip_runtime.h>

#define NA 3
#define NCLS 3
#define NB 12
#define BATCH 128
#define UNITS 1792

// Anchors per scale (already divided by stride)
__device__ __constant__ float AWc[3][3] = {{3.625f, 4.875f, 11.65625f},
                                           {1.875f, 3.875f, 3.6875f},
                                           {1.25f,  2.0f,   4.125f}};
__device__ __constant__ float AHc[3][3] = {{2.8125f, 6.1875f, 10.1875f},
                                           {3.8125f, 2.8125f, 7.4375f},
                                           {1.625f,  3.75f,   2.875f}};

__device__ __forceinline__ float safelog(float x) {
    return fmaxf(__logf(x), -100.0f);
}

// skey per box: bits 0..15 = rem (gj*G+gi), bits 16..22 = flags, bits 24..25 = cls
// flags: bits 0..2 = clear mask per anchor (ANDed with valid)
//        bits 4..6 = obj mask (valid ? 1<<best : 0)

template <int G, int S, int ITER>
__device__ __forceinline__ float scale_body(int b, int chunk,
        const float* __restrict__ outp,
        const float* __restrict__ boxes,
        const int* __restrict__ labels,
        int* skey, float* sdat)
{
    constexpr int GG = G * G;
    constexpr int CELLS = NA * GG;
    const int tid = threadIdx.x;

    // ---- in-block box meta (threads 0..11) ----
    if (tid < NB) {
        float4 bx = ((const float4*)boxes)[b * NB + tid];
        int lab = labels[b * NB + tid];
        bool valid = lab < NCLS;

        float bw = bx.z * (float)G, bh = bx.w * (float)G;
        int gi = min(max((int)(bx.x * (float)G), 0), G - 1);
        int gj = min(max((int)(bx.y * (float)G), 0), G - 1);

        float iou[3]; int best = 0; float bi = -1.0f;
#pragma unroll
        for (int a = 0; a < 3; a++) {
            float aw = AWc[S][a], ah = AHc[S][a];
            float inter = fminf(aw, bw) * fminf(ah, bh);
            float uni = aw * ah + 1e-16f + bw * bh - inter;
            iou[a] = inter / uni;
            if (iou[a] > bi) { bi = iou[a]; best = a; }
        }
        int flags = 0;
        if (valid) {
#pragma unroll
            for (int a = 0; a < 3; a++)
                if (iou[a] > 0.5f || a == best) flags |= (1 << a);
            flags |= (1 << (4 + best));
        }
        int cls = min(max(lab, 0), NCLS - 1);
        skey[tid] = (gj * G + gi) | (flags << 16) | (cls << 24);
        sdat[tid]      = valid ? __logf(bw / AWc[S][best] + 1e-16f) : 0.0f;
        sdat[NB + tid] = valid ? __logf(bh / AHc[S][best] + 1e-16f) : 0.0f;
    }
    __syncthreads();

    // box keys -> SGPRs (uniform across block)
    int rk[NB];
#pragma unroll
    for (int n = 0; n < NB; n++) rk[n] = __builtin_amdgcn_readfirstlane(skey[n]);

    const float* outb = outp + (size_t)b * CELLS * 8;
    float acc = 0.0f;
    const int base = chunk * (256 * ITER);

#pragma unroll
    for (int k = 0; k < ITER; k++) {
        int c = base + k * 256 + tid;
        if (c < CELLS) {
            const float* cp = outb + (size_t)c * 8;
            float4 q1 = *(const float4*)(cp + 4);   // conf + 3 class probs
            float conf = q1.x;

            // per-wave SALU prefilter: can any box land in this wave's rem range?
            int cw = __builtin_amdgcn_readfirstlane(c) & ~63;
            int aw = cw / GG;
            int r0 = cw - aw * GG;
            bool maybe = (r0 + 63 >= GG);           // wave straddles anchor plane
#pragma unroll
            for (int n = 0; n < NB; n++)
                maybe = maybe || ((unsigned)((rk[n] & 0xFFFF) - r0) < 64u);

            float keepv = 1.0f;
            int objn = -1;
            int a = 0;
            if (maybe) {
                a = c / GG;
                int rem = c - a * GG;
#pragma unroll
                for (int n = 0; n < NB; n++) {
                    int pk = rk[n];
                    if ((pk & 0xFFFF) == rem) {
                        int fl = pk >> 16;
                        if ((fl >> a) & 1) keepv = 0.0f;
                        if ((fl >> (4 + a)) & 1) objn = n;
                    }
                }
            }

            float loss = -0.5f * keepv * safelog(1.0f - conf);  // NOOBJ_SCALE*bce(conf,0)

            if (objn >= 0) {                        // rare: <=12 cells per image-scale
                float4 q0 = *(const float4*)cp;
                int pk = rk[objn];
                int cls = (pk >> 24) & 3;
                float tw = sdat[objn], th = sdat[NB + objn];
                float aws = AWc[S][a], ahs = AHc[S][a];
                float px = q0.x - floorf(q0.x);
                float py = q0.y - floorf(q0.y);
                float pw = __logf(q0.z / aws + 1e-16f);
                float ph = __logf(q0.w / ahs + 1e-16f);
                float dw = pw - tw, dh = ph - th;
                loss += px * px + py * py + dw * dw + dh * dh;
                loss += -5.0f * safelog(conf);      // OBJ_SCALE*bce(conf,1)
                float c0 = q1.y, c1 = q1.z, c2 = q1.w;
                loss -= (cls == 0) ? safelog(c0) : safelog(1.0f - c0);
                loss -= (cls == 1) ? safelog(c1) : safelog(1.0f - c1);
                loss -= (cls == 2) ? safelog(c2) : safelog(1.0f - c2);
            }
            acc += loss;
        }
    }
    return acc;
}

__launch_bounds__(256)
__global__ void fused_loss(const float* __restrict__ oL,
                           const float* __restrict__ oM,
                           const float* __restrict__ oS,
                           const float* __restrict__ boxes,
                           const int* __restrict__ labels,
                           float* __restrict__ partials,
                           unsigned int* __restrict__ counter,
                           float* __restrict__ out)
{
    __shared__ int skey[NB];
    __shared__ float sdat[2 * NB];
    __shared__ float red[256];
    __shared__ int isLast;

    const int u = blockIdx.x;
    const int tid = threadIdx.x;

    float acc;
    if (u < 128) {
        acc = scale_body<19, 0, 5>(u, 0, oL, boxes, labels, skey, sdat);
    } else if (u < 640) {
        int r = u - 128;
        acc = scale_body<38, 1, 5>(r >> 2, r & 3, oM, boxes, labels, skey, sdat);
    } else {
        int r = u - 640;
        acc = scale_body<76, 2, 8>(r / 9, r % 9, oS, boxes, labels, skey, sdat);
    }

    red[tid] = acc;
    __syncthreads();
#pragma unroll
    for (int s = 128; s > 0; s >>= 1) {
        if (tid < s) red[tid] += red[tid + s];
        __syncthreads();
    }

    if (tid == 0) {
        partials[u] = red[0];
        __threadfence();
        isLast = (atomicAdd(counter, 1u) == UNITS - 1);
    }
    __syncthreads();

    if (isLast) {   // fixed-order final sum -> bit-identical regardless of which block runs it
        __threadfence();
        float a2 = 0.0f;
#pragma unroll
        for (int i = 0; i < 7; i++) a2 += partials[tid + i * 256];
        red[tid] = a2;
        __syncthreads();
#pragma unroll
        for (int s = 128; s > 0; s >>= 1) {
            if (tid < s) red[tid] += red[tid + s];
            __syncthreads();
        }
        if (tid == 0) out[0] = red[0] * (1.0f / (float)BATCH);
    }
}

extern "C" void kernel_launch(void* const* d_in, const int* in_sizes, int n_in,
                              void* d_out, int out_size, void* d_ws, size_t ws_size,
                              hipStream_t stream) {
    const float* oL     = (const float*)d_in[0];
    const float* oM     = (const float*)d_in[1];
    const float* oS     = (const float*)d_in[2];
    const float* boxes  = (const float*)d_in[3];
    const int*   labels = (const int*)d_in[4];

    float* partials   = (float*)d_ws;                         // UNITS floats
    unsigned* counter = (unsigned*)((char*)d_ws + UNITS * sizeof(float));

    hipMemsetAsync(counter, 0, sizeof(unsigned), stream);     // replay-safe counter reset
    fused_loss<<<UNITS, 256, 0, stream>>>(oL, oM, oS, boxes, labels,
                                          partials, counter, (float*)d_out);
}